// Round 3
// baseline (1008.618 us; speedup 1.0000x reference)
//
#include <hip/hip_runtime.h>
#include <hip/hip_fp16.h>

typedef unsigned int u32;

#define OUTD   4096
#define BATCH  4096
#define DEXC   8192
#define DINH   2048
#define KEXC   32
#define KINH   16
#define NB     4
#define NCHUNK 4
#define GRID_MAIN (BATCH / (NB * NCHUNK))        // 256
#define BUF_BYTES (DEXC * 8 + DINH * 4)          // 72 KiB per buffer
#define LDS_BYTES (2 * BUF_BYTES)                // 147456 B <= 160 KiB
constexpr int CAP = 1024;

// ---------------- fused top-k + exp + pack ----------------
// Emits (fp16(exp(w)*wscale)<<16)|idx, k-major-interleaved: main loads uint4
// at [kk*OUTD + o]. Inh wscale=1/256 folds the unorm8 decode scale into w.
template<int IN, int K>
__device__ __forceinline__ void topk_row(const float* __restrict__ pw, u32* __restrict__ pack_out,
                                         int o, float T0, float wscale,
                                         float* s_val, int* s_idx, int* s_red, int* s_misc) {
  constexpr int V4 = IN / 1024;
  const int tid = threadIdx.x;
  const float4* row = (const float4*)(pw + (size_t)o * IN);

  float4 v[V4];
#pragma unroll
  for (int c = 0; c < V4; ++c) v[c] = row[tid + c * 256];

  float T = T0;
  int C = 0;
  for (int iter = 0; iter < 50; ++iter) {
    int cnt = 0;
#pragma unroll
    for (int c = 0; c < V4; ++c)
      cnt += (v[c].x > T) + (v[c].y > T) + (v[c].z > T) + (v[c].w > T);
#pragma unroll
    for (int off = 32; off >= 1; off >>= 1) cnt += __shfl_down(cnt, off, 64);
    if ((tid & 63) == 0) s_red[tid >> 6] = cnt;
    __syncthreads();
    if (tid == 0) s_misc[0] = s_red[0] + s_red[1] + s_red[2] + s_red[3];
    __syncthreads();
    C = s_misc[0];
    if (C >= K && C <= CAP) break;
    if (iter >= 47)    T = -1e30f;
    else if (C < K)    T -= 0.75f;
    else               T += 0.375f;
    __syncthreads();
  }

  if (tid == 0) s_misc[1] = 0;
  __syncthreads();
#pragma unroll
  for (int c = 0; c < V4; ++c) {
    const float vv[4] = {v[c].x, v[c].y, v[c].z, v[c].w};
#pragma unroll
    for (int q = 0; q < 4; ++q) {
      if (vv[q] > T) {
        int p = atomicAdd(&s_misc[1], 1);
        if (p < CAP) { s_val[p] = vv[q]; s_idx[p] = (tid + c * 256) * 4 + q; }
      }
    }
  }
  __syncthreads();
  C = s_misc[1] < CAP ? s_misc[1] : CAP;

  for (int t = tid; t < C; t += 256) {
    const float mv = s_val[t];
    const int   mi = s_idx[t];
    int r = 0;
    for (int q = 0; q < C; ++q) {
      const float qv = s_val[q];
      r += ((qv > mv) || (qv == mv && s_idx[q] < mi)) ? 1 : 0;
    }
    if (r < K) {
      const float w = __expf(mv) * wscale;
      const u32 hb = (u32)__half_as_ushort(__float2half(w));
      pack_out[((r >> 2) * OUTD + o) * 4 + (r & 3)] = (hb << 16) | (u32)mi;
    }
  }
}

__global__ __launch_bounds__(256)
void topk_both(const float* __restrict__ pwe, const float* __restrict__ pwi,
               u32* __restrict__ packE, u32* __restrict__ packI) {
  __shared__ float s_val[CAP];
  __shared__ int   s_idx[CAP];
  __shared__ int   s_red[4];
  __shared__ int   s_misc[2];
  if (blockIdx.x < OUTD)
    topk_row<DEXC, KEXC>(pwe, packE, blockIdx.x, 2.5f, 1.0f, s_val, s_idx, s_red, s_misc);
  else
    topk_row<DINH, KINH>(pwi, packI, blockIdx.x - OUTD, 2.0f, 1.0f / 256.0f,
                         s_val, s_idx, s_red, s_misc);
}

// ---------------- main gather kernel ----------------
__device__ __forceinline__ u32 pack2f(float a, float b) {
  __half2 h = __floats2half2_rn(a, b);
  return __builtin_bit_cast(u32, h);
}

__device__ __forceinline__ void accumE(u32 u, const uint2* __restrict__ lds, __half2 acc[2]) {
  const u32 j  = u & 0xFFFFu;
  const u32 wb = __builtin_amdgcn_perm(u, u, 0x03020302u);   // hi16 replicated {w,w}
  const __half2 w2 = __builtin_bit_cast(__half2, wb);
  const uint2 xf = lds[j];                                   // ds_read_b64 fp16 x[j][b0..b3]
  acc[0] = __hfma2(w2, __builtin_bit_cast(__half2, xf.x), acc[0]);
  acc[1] = __hfma2(w2, __builtin_bit_cast(__half2, xf.y), acc[1]);
}

__device__ __forceinline__ void accumI(u32 u, const u32* __restrict__ lds, __half2 acc[2]) {
  const u32 j  = u & 0xFFFFu;
  const u32 wb = __builtin_amdgcn_perm(u, u, 0x03020302u);   // {w',w'}, w' = exp(w)/256
  const __half2 w2 = __builtin_bit_cast(__half2, wb);
  const u32 v = lds[j];                                      // ds_read_b32: unorm8 x4 batch
  // v_perm: sel 0-3 -> src1 bytes, 4-7 -> src0 bytes. Build fp16 (1024+v_b).
  const u32 h01 = __builtin_amdgcn_perm(0x64646464u, v, 0x04010400u);  // {v0,v1}
  const u32 h23 = __builtin_amdgcn_perm(0x64646464u, v, 0x04030402u);  // {v2,v3}
  const __half2 kneg = __builtin_bit_cast(__half2, 0xE400E400u);       // {-1024,-1024}
  const __half2 x01 = __hadd2(__builtin_bit_cast(__half2, h01), kneg); // = 256*x
  const __half2 x23 = __hadd2(__builtin_bit_cast(__half2, h23), kneg);
  acc[0] = __hfma2(w2, x01, acc[0]);
  acc[1] = __hfma2(w2, x23, acc[1]);
}

__device__ __forceinline__ void load_chunk(const float* __restrict__ xe,
                                           const float* __restrict__ xi,
                                           int b0, int tid, float4 se[8], float4 si[4]) {
  const float4* Xe = (const float4*)xe;
  const float4* Xi = (const float4*)xi;
#pragma unroll
  for (int p = 0; p < 2; ++p) {
    const int j4 = tid + p * 1024;
#pragma unroll
    for (int r = 0; r < 4; ++r)
      se[p * 4 + r] = Xe[(size_t)(b0 + r) * (DEXC / 4) + j4];
  }
  if (tid < DINH / 4) {
#pragma unroll
    for (int r = 0; r < 4; ++r)
      si[r] = Xi[(size_t)(b0 + r) * (DINH / 4) + tid];
  }
}

__device__ __forceinline__ u32 q8(float x) {     // unorm8 with rounding, x in [0,1)
  return (u32)fminf(x * 256.0f + 0.5f, 255.0f);
}

__device__ __forceinline__ void write_chunk(char* __restrict__ buf, int tid,
                                            const float4 se[8], const float4 si[4]) {
  uint2* ldsE = (uint2*)buf;
  u32*   ldsI = (u32*)(buf + DEXC * 8);
#pragma unroll
  for (int p = 0; p < 2; ++p) {
    const int j4 = tid + p * 1024;
    uint2* dst = ldsE + j4 * 4;
    const float4 r0 = se[p * 4 + 0], r1 = se[p * 4 + 1], r2 = se[p * 4 + 2], r3 = se[p * 4 + 3];
    dst[0] = {pack2f(r0.x, r1.x), pack2f(r2.x, r3.x)};
    dst[1] = {pack2f(r0.y, r1.y), pack2f(r2.y, r3.y)};
    dst[2] = {pack2f(r0.z, r1.z), pack2f(r2.z, r3.z)};
    dst[3] = {pack2f(r0.w, r1.w), pack2f(r2.w, r3.w)};
  }
  if (tid < DINH / 4) {
    uint4 w;
    w.x = q8(si[0].x) | (q8(si[1].x) << 8) | (q8(si[2].x) << 16) | (q8(si[3].x) << 24);
    w.y = q8(si[0].y) | (q8(si[1].y) << 8) | (q8(si[2].y) << 16) | (q8(si[3].y) << 24);
    w.z = q8(si[0].z) | (q8(si[1].z) << 8) | (q8(si[2].z) << 16) | (q8(si[3].z) << 24);
    w.w = q8(si[0].w) | (q8(si[1].w) << 8) | (q8(si[2].w) << 16) | (q8(si[3].w) << 24);
    ((uint4*)ldsI)[tid] = w;                     // 4 j-words, ds_write_b128
  }
}

__global__ __launch_bounds__(1024, 4)
void dendrite_main(const float* __restrict__ xe, const float* __restrict__ xi,
                   const uint4* __restrict__ pe4, const uint4* __restrict__ pi4,
                   float* __restrict__ out) {
  extern __shared__ char smem[];
  const int tid = threadIdx.x;
  const int b0  = blockIdx.x * NB * NCHUNK;

  float4 se[8];
  float4 si[4];

  // prologue: stage chunk 0 into buf 0
  load_chunk(xe, xi, b0, tid, se, si);
  write_chunk(smem, tid, se, si);
  __syncthreads();

  for (int c = 0; c < NCHUNK; ++c) {
    if (c + 1 < NCHUNK) load_chunk(xe, xi, b0 + (c + 1) * NB, tid, se, si);  // VMEM prefetch

    const char* buf = smem + (size_t)(c & 1) * BUF_BYTES;
    const uint2* ldsE = (const uint2*)buf;
    const u32*   ldsI = (const u32*)(buf + DEXC * 8);
    const int bb = b0 + c * NB;

#pragma unroll
    for (int r = 0; r < OUTD / 1024; ++r) {
      const int o = tid + r * 1024;
      uint4 pk[KEXC / 4 + KINH / 4];
#pragma unroll
      for (int kk = 0; kk < KEXC / 4; ++kk) pk[kk] = pe4[kk * OUTD + o];     // L2-hot
#pragma unroll
      for (int kk = 0; kk < KINH / 4; ++kk) pk[KEXC / 4 + kk] = pi4[kk * OUTD + o];

      const __half2 z = __builtin_bit_cast(__half2, 0u);
      __half2 e[2]  = {z, z};
      __half2 ia[2] = {z, z};
#pragma unroll
      for (int kk = 0; kk < KEXC / 4; ++kk) {
        accumE(pk[kk].x, ldsE, e); accumE(pk[kk].y, ldsE, e);
        accumE(pk[kk].z, ldsE, e); accumE(pk[kk].w, ldsE, e);
      }
#pragma unroll
      for (int kk = 0; kk < KINH / 4; ++kk) {
        const uint4 p = pk[KEXC / 4 + kk];
        accumI(p.x, ldsI, ia); accumI(p.y, ldsI, ia);
        accumI(p.z, ldsI, ia); accumI(p.w, ldsI, ia);
      }
#pragma unroll
      for (int d = 0; d < 2; ++d) {
        const float2 ev = __half22float2(e[d]);
        const float2 iv = __half22float2(ia[d]);
        out[(size_t)(bb + 2 * d    ) * OUTD + o] = ev.x * __builtin_amdgcn_rcpf(1.0f + iv.x);
        out[(size_t)(bb + 2 * d + 1) * OUTD + o] = ev.y * __builtin_amdgcn_rcpf(1.0f + iv.y);
      }
    }

    if (c + 1 < NCHUNK) write_chunk((char*)smem + (size_t)((c + 1) & 1) * BUF_BYTES, tid, se, si);
    __syncthreads();
  }
}

extern "C" void kernel_launch(void* const* d_in, const int* in_sizes, int n_in,
                              void* d_out, int out_size, void* d_ws, size_t ws_size,
                              hipStream_t stream) {
  const float* xe  = (const float*)d_in[0];
  const float* xi  = (const float*)d_in[1];
  const float* pwe = (const float*)d_in[2];
  const float* pwi = (const float*)d_in[3];
  u32* packE = (u32*)d_ws;                    // 512 KiB
  u32* packI = packE + OUTD * KEXC;           // 256 KiB

  (void)hipFuncSetAttribute((const void*)dendrite_main,
                            hipFuncAttributeMaxDynamicSharedMemorySize, LDS_BYTES);

  topk_both<<<2 * OUTD, 256, 0, stream>>>(pwe, pwi, packE, packI);
  dendrite_main<<<GRID_MAIN, 1024, LDS_BYTES, stream>>>(
      xe, xi, (const uint4*)packE, (const uint4*)packI, (float*)d_out);
}